// Round 11
// baseline (179.425 us; speedup 1.0000x reference)
//
#include <hip/hip_runtime.h>

#define IN_DIM  128
#define HID_DIM 64
#define OUT_DIM 32
#define BPN   256     // nodes per destination bin (dstLocal fits 8 bits)
#define CHUNK 4096    // edges per partition block (256 thr x 16)

// ---------------------------------------------------------------------------
// pack two f32 -> (bf16,bf16) in one u32, round-to-nearest-even
__device__ __forceinline__ unsigned pack_bf16(float a, float b) {
  unsigned ua = __float_as_uint(a), ub = __float_as_uint(b);
  ua += 0x7FFFu + ((ua >> 16) & 1u);
  ub += 0x7FFFu + ((ub >> 16) & 1u);
  return (ua >> 16) | (ub & 0xFFFF0000u);
}
__device__ __forceinline__ float bf_lo(unsigned v) { return __uint_as_float(v << 16); }
__device__ __forceinline__ float bf_hi(unsigned v) { return __uint_as_float(v & 0xFFFF0000u); }

__device__ __forceinline__ int load_idx(const void* p, long long i, int is64) {
  return is64 ? (int)((const long long*)p)[i] : ((const int*)p)[i];
}

// In-block dtype probe: first wave checks 64 u64 words; int32 data read as
// u64 packs two values -> >= N almost surely. Result broadcast via LDS.
__device__ __forceinline__ int block_detect(const void* eidx, long long E,
                                            long long N, int* sflag) {
  bool ok = true;
  long long cap = E < 64 ? E : 64;
  if (threadIdx.x < cap)
    ok = ((const unsigned long long*)eidx)[threadIdx.x] < (unsigned long long)N;
  unsigned long long ball = __ballot(ok);
  if (threadIdx.x == 0) *sflag = (ball == ~0ULL) ? 1 : 0;
  __syncthreads();
  return *sflag;
}

// ---------------------------------------------------------------------------
// P1: per-bin edge counts; 4 per-wave LDS histograms to cut atomic conflicts.
__global__ __launch_bounds__(256) void k_p1(const void* eidx, long long E,
                                            int* __restrict__ binCnt,
                                            long long N, int nbin) {
  __shared__ int hist[4 * 512];
  __shared__ int sflag;
  for (int i = threadIdx.x; i < 4 * 512; i += 256) hist[i] = 0;
  int f = block_detect(eidx, E, N, &sflag);   // includes __syncthreads
  int* h = hist + 512 * (threadIdx.x >> 6);
  long long b0 = (long long)blockIdx.x * CHUNK;
#pragma unroll
  for (int i = 0; i < CHUNK / 256; ++i) {
    long long e = b0 + i * 256 + threadIdx.x;
    if (e < E) atomicAdd(&h[load_idx(eidx, E + e, f) >> 8], 1);
  }
  __syncthreads();
  for (int i = threadIdx.x; i < nbin; i += 256) {
    int s = hist[i] + hist[512 + i] + hist[1024 + i] + hist[1536 + i];
    if (s) atomicAdd(&binCnt[i], s);
  }
}

// exclusive scan of binCnt -> binBase, binCursor (nbin <= 512);
// spare threads zero the dummy rows (row N) of xw1b/xw2b.
__global__ __launch_bounds__(512) void k_scanbins(const int* __restrict__ binCnt,
                                                  int* __restrict__ binBase,
                                                  int* __restrict__ binCursor, int nbin,
                                                  unsigned* __restrict__ xw1b,
                                                  unsigned* __restrict__ xw2b, int N) {
  __shared__ int s[512];
  int t = threadIdx.x;
  if (t < HID_DIM / 2) xw1b[(size_t)N * (HID_DIM / 2) + t] = 0;
  else if (t < HID_DIM / 2 + OUT_DIM / 2)
    xw2b[(size_t)N * (OUT_DIM / 2) + (t - HID_DIM / 2)] = 0;
  int own = (t < nbin) ? binCnt[t] : 0;
  s[t] = own; __syncthreads();
  for (int o = 1; o < 512; o <<= 1) {
    int v = (t >= o) ? s[t - o] : 0;
    __syncthreads();
    s[t] += v;
    __syncthreads();
  }
  if (t < nbin) { int ex = s[t] - own; binBase[t] = ex; binCursor[t] = ex; }
}

// P2: scatter edges into bin-contiguous regions, packed {dstLocal<<17 | src}.
__global__ __launch_bounds__(256) void k_p2(const void* eidx, long long E,
                                            int* __restrict__ binCursor,
                                            unsigned* __restrict__ entry1,
                                            long long N, int nbin) {
  __shared__ int hist[512];
  __shared__ int basel[512];
  __shared__ int sflag;
  for (int i = threadIdx.x; i < nbin; i += 256) hist[i] = 0;
  int f = block_detect(eidx, E, N, &sflag);
  long long b0 = (long long)blockIdx.x * CHUNK;
#pragma unroll
  for (int i = 0; i < CHUNK / 256; ++i) {
    long long e = b0 + i * 256 + threadIdx.x;
    if (e < E) atomicAdd(&hist[load_idx(eidx, E + e, f) >> 8], 1);
  }
  __syncthreads();
  for (int i = threadIdx.x; i < nbin; i += 256) {
    int h = hist[i];
    basel[i] = h ? atomicAdd(&binCursor[i], h) : 0;
  }
  __syncthreads();
  for (int i = threadIdx.x; i < nbin; i += 256) hist[i] = 0;
  __syncthreads();
#pragma unroll
  for (int i = 0; i < CHUNK / 256; ++i) {
    long long e = b0 + i * 256 + threadIdx.x;
    if (e < E) {
      int r = load_idx(eidx, e, f);
      int c = load_idx(eidx, E + e, f);
      int bin = c >> 8;
      int rk = atomicAdd(&hist[bin], 1);
      entry1[basel[bin] + rk] = ((unsigned)(c & 255) << 17) | (unsigned)r;
    }
  }
}

// P3: one block per bin -> per-node CSR with 8-aligned runs (pad = dummy N).
__global__ __launch_bounds__(256) void k_p3(const unsigned* __restrict__ entry1,
                                            const int* __restrict__ binBase,
                                            const int* __restrict__ binCnt,
                                            int* __restrict__ entry2,
                                            int* __restrict__ base,
                                            int* __restrict__ cnt,
                                            float* __restrict__ dinv, int N) {
  __shared__ int hist[BPN];
  __shared__ int off[BPN];
  __shared__ int s[BPN];
  int t = threadIdx.x;
  int b = blockIdx.x;
  int lo = binBase[b];
  int hi = lo + binCnt[b];
  int pBB = ((lo + 7) & ~7) + 8 * BPN * b;   // padded, 8-aligned bin base
  int n0 = b * BPN;
  hist[t] = 0;
  __syncthreads();
  for (int i = lo + t; i < hi; i += 256)
    atomicAdd(&hist[entry1[i] >> 17], 1);
  __syncthreads();
  int own  = hist[t];
  int own8 = (own + 7) & ~7;
  s[t] = own8; __syncthreads();
  for (int o = 1; o < 256; o <<= 1) {
    int v = (t >= o) ? s[t - o] : 0;
    __syncthreads();
    s[t] += v;
    __syncthreads();
  }
  int node = n0 + t;
  int ex = pBB + (s[t] - own8);              // 8-aligned absolute slot
  if (node < N) {
    base[node] = ex;
    cnt[node]  = own;
    dinv[node] = rsqrtf((float)own + 1.0f);
    for (int q = own; q < own8; ++q) entry2[ex + q] = N;  // dummy pads
  }
  off[t] = ex;
  __syncthreads();
  for (int i = lo + t; i < hi; i += 256) {
    unsigned v = entry1[i];
    int pos = atomicAdd(&off[v >> 17], 1);
    entry2[pos] = (int)(v & 0x1FFFFu);
  }
}

// ---------------------------------------------------------------------------
// xw1b[r] = bf16( dinv[r] * (x[r] @ W1) )   packed 2-per-u32, [N][32] u32.
// 256 thr -> 64 rows x 64 cols, 4x4 per thread. NO LDS: x addresses are
// shared by 16 lanes (L1 broadcast), W1 is 32 KB L1-resident. Zero LDS ->
// occupancy is grid-limited (~24 waves/CU), hiding the load latency the
// LDS variants could not (rounds 9-10: occ 15%, regressed).
__global__ __launch_bounds__(256) void k_gemm1(const float* __restrict__ x,
                                               const float* __restrict__ W1,
                                               const float* __restrict__ dinv,
                                               unsigned* __restrict__ xw1b, int N) {
  const int rg = threadIdx.x >> 4;         // 0..15 row group
  const int jg = threadIdx.x & 15;         // 0..15 col group
  const int r0 = blockIdx.x * 64 + rg * 4;
  const int j0 = jg * 4;

  int rc[4];
#pragma unroll
  for (int d = 0; d < 4; ++d) { int r = r0 + d; rc[d] = r < N ? r : N - 1; }

  float acc[4][4];
#pragma unroll
  for (int d = 0; d < 4; ++d)
#pragma unroll
    for (int q = 0; q < 4; ++q) acc[d][q] = 0.f;

#pragma unroll 2
  for (int k4 = 0; k4 < IN_DIM / 4; ++k4) {
    float4 xv[4];
#pragma unroll
    for (int d = 0; d < 4; ++d)
      xv[d] = *(const float4*)(x + (size_t)rc[d] * IN_DIM + 4 * k4);
    float4 wv[4];
#pragma unroll
    for (int q = 0; q < 4; ++q)
      wv[q] = *(const float4*)(W1 + (4 * k4 + q) * HID_DIM + j0);
#pragma unroll
    for (int d = 0; d < 4; ++d) {
      acc[d][0] += xv[d].x * wv[0].x + xv[d].y * wv[1].x + xv[d].z * wv[2].x + xv[d].w * wv[3].x;
      acc[d][1] += xv[d].x * wv[0].y + xv[d].y * wv[1].y + xv[d].z * wv[2].y + xv[d].w * wv[3].y;
      acc[d][2] += xv[d].x * wv[0].z + xv[d].y * wv[1].z + xv[d].z * wv[2].z + xv[d].w * wv[3].z;
      acc[d][3] += xv[d].x * wv[0].w + xv[d].y * wv[1].w + xv[d].z * wv[2].w + xv[d].w * wv[3].w;
    }
  }

#pragma unroll
  for (int d = 0; d < 4; ++d) {
    int r = r0 + d;
    if (r < N) {
      float dv = dinv[r];
      uint2 pv;
      pv.x = pack_bf16(dv * acc[d][0], dv * acc[d][1]);
      pv.y = pack_bf16(dv * acc[d][2], dv * acc[d][3]);
      *(uint2*)(xw1b + (size_t)r * (HID_DIM / 2) + 2 * jg) = pv;
    }
  }
}

// ---------------------------------------------------------------------------
// gather layer 1 + relu + GEMM2, wave-self-contained; 8-deep payload MLP.
// 16 nodes/block; each wave owns 4 nodes (16 lanes/node, dwordx2 payloads).
__global__ __launch_bounds__(256) void k_gather1(const int* __restrict__ entry,
                                                 const int* __restrict__ base,
                                                 const int* __restrict__ cnt,
                                                 const float* __restrict__ dinv,
                                                 const uint2* __restrict__ xw1b2,
                                                 const float* __restrict__ b1,
                                                 const float* __restrict__ W2,
                                                 unsigned* __restrict__ xw2b, int N) {
  __shared__ float w2s[HID_DIM * OUT_DIM];  // 8 KB
  __shared__ float hs[16][68];              // row stride 272 B (16B-aligned)
  __shared__ float dvs[16];
  for (int i = threadIdx.x; i < HID_DIM * OUT_DIM; i += 256) w2s[i] = W2[i];
  __syncthreads();   // w2s ready; only barrier in the kernel

  const int wv   = threadIdx.x >> 6;   // wave 0..3
  const int ln   = threadIdx.x & 63;
  const int slot = wv * 4 + (ln >> 4); // node slot 0..15 (4 per wave)
  const int lane = ln & 15;            // lane owns dims 4*lane..4*lane+3
  const int node = blockIdx.x * 16 + slot;

  if (node < N) {
    int st = base[node];
    int it = (cnt[node] + 7) >> 3;
    float ax[4], ay[4], az[4], aw[4];
#pragma unroll
    for (int q = 0; q < 4; ++q) { ax[q] = ay[q] = az[q] = aw[q] = 0.f; }
    for (int i = 0; i < it; ++i) {
      int4 ea = *(const int4*)(entry + st + 8 * i);
      int4 eb = *(const int4*)(entry + st + 8 * i + 4);
      uint2 v0 = xw1b2[(size_t)ea.x * 16 + lane];
      uint2 v1 = xw1b2[(size_t)ea.y * 16 + lane];
      uint2 v2 = xw1b2[(size_t)ea.z * 16 + lane];
      uint2 v3 = xw1b2[(size_t)ea.w * 16 + lane];
      uint2 v4 = xw1b2[(size_t)eb.x * 16 + lane];
      uint2 v5 = xw1b2[(size_t)eb.y * 16 + lane];
      uint2 v6 = xw1b2[(size_t)eb.z * 16 + lane];
      uint2 v7 = xw1b2[(size_t)eb.w * 16 + lane];
      ax[0] += bf_lo(v0.x) + bf_lo(v4.x); ay[0] += bf_hi(v0.x) + bf_hi(v4.x);
      az[0] += bf_lo(v0.y) + bf_lo(v4.y); aw[0] += bf_hi(v0.y) + bf_hi(v4.y);
      ax[1] += bf_lo(v1.x) + bf_lo(v5.x); ay[1] += bf_hi(v1.x) + bf_hi(v5.x);
      az[1] += bf_lo(v1.y) + bf_lo(v5.y); aw[1] += bf_hi(v1.y) + bf_hi(v5.y);
      ax[2] += bf_lo(v2.x) + bf_lo(v6.x); ay[2] += bf_hi(v2.x) + bf_hi(v6.x);
      az[2] += bf_lo(v2.y) + bf_lo(v6.y); aw[2] += bf_hi(v2.y) + bf_hi(v6.y);
      ax[3] += bf_lo(v3.x) + bf_lo(v7.x); ay[3] += bf_hi(v3.x) + bf_hi(v7.x);
      az[3] += bf_lo(v3.y) + bf_lo(v7.y); aw[3] += bf_hi(v3.y) + bf_hi(v7.y);
    }
    uint2 vs = xw1b2[(size_t)node * 16 + lane];  // self-loop
    float dv = dinv[node];
    float4 bb = *(const float4*)(b1 + 4 * lane);
    float h0 = dv * ((ax[0] + ax[1]) + (ax[2] + ax[3]) + bf_lo(vs.x)) + bb.x;
    float h1 = dv * ((ay[0] + ay[1]) + (ay[2] + ay[3]) + bf_hi(vs.x)) + bb.y;
    float h2 = dv * ((az[0] + az[1]) + (az[2] + az[3]) + bf_lo(vs.y)) + bb.z;
    float h3 = dv * ((aw[0] + aw[1]) + (aw[2] + aw[3]) + bf_hi(vs.y)) + bb.w;
    float4 hv;
    hv.x = h0 > 0.f ? h0 : 0.f;
    hv.y = h1 > 0.f ? h1 : 0.f;
    hv.z = h2 > 0.f ? h2 : 0.f;
    hv.w = h3 > 0.f ? h3 : 0.f;
    *(float4*)(&hs[slot][4 * lane]) = hv;
    if (lane == 0) dvs[slot] = dv;
  }
  __builtin_amdgcn_wave_barrier();  // keep compiler from reordering DS ops

  if (node < N) {
    float acc0 = 0.f, acc1 = 0.f;
#pragma unroll
    for (int jj = 0; jj < HID_DIM; ++jj) {
      float hv = hs[slot][jj];
      float2 w = *(const float2*)(w2s + jj * OUT_DIM + 2 * lane);
      acc0 += hv * w.x;
      acc1 += hv * w.y;
    }
    float dv = dvs[slot];
    xw2b[(size_t)node * (OUT_DIM / 2) + lane] = pack_bf16(dv * acc0, dv * acc1);
  }
}

// ---------------------------------------------------------------------------
// gather layer 2 + relu -> d_out. 32 nodes/block, 8 lanes/node, 8-deep MLP.
__global__ __launch_bounds__(256) void k_gather2(const int* __restrict__ entry,
                                                 const int* __restrict__ base,
                                                 const int* __restrict__ cnt,
                                                 const float* __restrict__ dinv,
                                                 const uint2* __restrict__ xw2b2,
                                                 const float* __restrict__ b2,
                                                 float* __restrict__ out, int N) {
  const int nl   = threadIdx.x >> 3;   // 0..31
  const int lane = threadIdx.x & 7;    // lane owns dims 4*lane..4*lane+3
  const int node = blockIdx.x * 32 + nl;
  if (node >= N) return;
  int st = base[node];
  int it = (cnt[node] + 7) >> 3;
  float ax[4], ay[4], az[4], aw[4];
#pragma unroll
  for (int q = 0; q < 4; ++q) { ax[q] = ay[q] = az[q] = aw[q] = 0.f; }
  for (int i = 0; i < it; ++i) {
    int4 ea = *(const int4*)(entry + st + 8 * i);
    int4 eb = *(const int4*)(entry + st + 8 * i + 4);
    uint2 v0 = xw2b2[(size_t)ea.x * 8 + lane];
    uint2 v1 = xw2b2[(size_t)ea.y * 8 + lane];
    uint2 v2 = xw2b2[(size_t)ea.z * 8 + lane];
    uint2 v3 = xw2b2[(size_t)ea.w * 8 + lane];
    uint2 v4 = xw2b2[(size_t)eb.x * 8 + lane];
    uint2 v5 = xw2b2[(size_t)eb.y * 8 + lane];
    uint2 v6 = xw2b2[(size_t)eb.z * 8 + lane];
    uint2 v7 = xw2b2[(size_t)eb.w * 8 + lane];
    ax[0] += bf_lo(v0.x) + bf_lo(v4.x); ay[0] += bf_hi(v0.x) + bf_hi(v4.x);
    az[0] += bf_lo(v0.y) + bf_lo(v4.y); aw[0] += bf_hi(v0.y) + bf_hi(v4.y);
    ax[1] += bf_lo(v1.x) + bf_lo(v5.x); ay[1] += bf_hi(v1.x) + bf_hi(v5.x);
    az[1] += bf_lo(v1.y) + bf_lo(v5.y); aw[1] += bf_hi(v1.y) + bf_hi(v5.y);
    ax[2] += bf_lo(v2.x) + bf_lo(v6.x); ay[2] += bf_hi(v2.x) + bf_hi(v6.x);
    az[2] += bf_lo(v2.y) + bf_lo(v6.y); aw[2] += bf_hi(v2.y) + bf_hi(v6.y);
    ax[3] += bf_lo(v3.x) + bf_lo(v7.x); ay[3] += bf_hi(v3.x) + bf_hi(v7.x);
    az[3] += bf_lo(v3.y) + bf_lo(v7.y); aw[3] += bf_hi(v3.y) + bf_hi(v7.y);
  }
  uint2 vs = xw2b2[(size_t)node * 8 + lane];  // self-loop
  float dv = dinv[node];
  float4 bb = *(const float4*)(b2 + 4 * lane);
  float v0 = dv * ((ax[0] + ax[1]) + (ax[2] + ax[3]) + bf_lo(vs.x)) + bb.x;
  float v1 = dv * ((ay[0] + ay[1]) + (ay[2] + ay[3]) + bf_hi(vs.x)) + bb.y;
  float v2 = dv * ((az[0] + az[1]) + (az[2] + az[3]) + bf_lo(vs.y)) + bb.z;
  float v3 = dv * ((aw[0] + aw[1]) + (aw[2] + aw[3]) + bf_hi(vs.y)) + bb.w;
  float4 res;
  res.x = v0 > 0.f ? v0 : 0.f;
  res.y = v1 > 0.f ? v1 : 0.f;
  res.z = v2 > 0.f ? v2 : 0.f;
  res.w = v3 > 0.f ? v3 : 0.f;
  *(float4*)(out + (size_t)node * OUT_DIM + 4 * lane) = res;
}

// ---------------------------------------------------------------------------
static inline size_t align256(size_t x) { return (x + 255) & ~(size_t)255; }

extern "C" void kernel_launch(void* const* d_in, const int* in_sizes, int n_in,
                              void* d_out, int out_size, void* d_ws, size_t ws_size,
                              hipStream_t stream) {
  const float* x   = (const float*)d_in[0];
  const float* W1  = (const float*)d_in[1];
  const float* b1  = (const float*)d_in[2];
  const float* W2  = (const float*)d_in[3];
  const float* b2  = (const float*)d_in[4];
  const void*  eidx = d_in[5];

  const int  N = in_sizes[0] / IN_DIM;             // 100000 (< 2^17 for packing)
  const long long E = (long long)in_sizes[5] / 2;  // 1600000
  const int  nbin = (N + BPN - 1) / BPN;           // 391 (<= 512)
  const int  np   = (int)((E + CHUNK - 1) / CHUNK);
  const size_t e2cap = (size_t)E + (size_t)8 * BPN * nbin + 64;

  char* ws = (char*)d_ws;
  size_t off = 0;
  int*      cnt       = (int*)(ws + off);      off += align256((size_t)N * 4);
  float*    dinv      = (float*)(ws + off);    off += align256((size_t)N * 4);
  int*      base      = (int*)(ws + off);      off += align256((size_t)N * 4);
  int*      binCnt    = (int*)(ws + off);      off += align256(512 * 4);
  int*      binBase   = (int*)(ws + off);      off += align256(512 * 4);
  int*      binCursor = (int*)(ws + off);      off += align256(512 * 4);
  unsigned* entry1    = (unsigned*)(ws + off); off += align256((size_t)E * 4);
  int*      entry2    = (int*)(ws + off);      off += align256(e2cap * 4);
  unsigned* xw1b      = (unsigned*)(ws + off); off += align256((size_t)(N + 1) * (HID_DIM / 2) * 4);
  unsigned* xw2b      = (unsigned*)(ws + off); off += align256((size_t)(N + 1) * (OUT_DIM / 2) * 4);
  float*    outf      = (float*)d_out;

  hipMemsetAsync(binCnt, 0, 512 * 4, stream);

  k_p1<<<np, 256, 0, stream>>>(eidx, E, binCnt, (long long)N, nbin);
  k_scanbins<<<1, 512, 0, stream>>>(binCnt, binBase, binCursor, nbin, xw1b, xw2b, N);
  k_p2<<<np, 256, 0, stream>>>(eidx, E, binCursor, entry1, (long long)N, nbin);
  k_p3<<<nbin, 256, 0, stream>>>(entry1, binBase, binCnt, entry2, base, cnt, dinv, N);

  k_gemm1<<<(N + 63) / 64, 256, 0, stream>>>(x, W1, dinv, xw1b, N);

  k_gather1<<<(N + 15) / 16, 256, 0, stream>>>(entry2, base, cnt, dinv,
                                               (const uint2*)xw1b, b1, W2, xw2b, N);

  k_gather2<<<(N + 31) / 32, 256, 0, stream>>>(entry2, base, cnt, dinv,
                                               (const uint2*)xw2b, b2, outf, N);
}

// Round 12
// 161.334 us; speedup vs baseline: 1.1121x; 1.1121x over previous
//
#include <hip/hip_runtime.h>

#define IN_DIM  128
#define HID_DIM 64
#define OUT_DIM 32
#define BPN   256     // nodes per destination bin (dstLocal fits 8 bits)
#define CHUNK 4096    // edges per partition block (256 thr x 16)

// ---------------------------------------------------------------------------
// pack two f32 -> (bf16,bf16) in one u32, round-to-nearest-even
__device__ __forceinline__ unsigned pack_bf16(float a, float b) {
  unsigned ua = __float_as_uint(a), ub = __float_as_uint(b);
  ua += 0x7FFFu + ((ua >> 16) & 1u);
  ub += 0x7FFFu + ((ub >> 16) & 1u);
  return (ua >> 16) | (ub & 0xFFFF0000u);
}
__device__ __forceinline__ float bf_lo(unsigned v) { return __uint_as_float(v << 16); }
__device__ __forceinline__ float bf_hi(unsigned v) { return __uint_as_float(v & 0xFFFF0000u); }

__device__ __forceinline__ int load_idx(const void* p, long long i, int is64) {
  return is64 ? (int)((const long long*)p)[i] : ((const int*)p)[i];
}

// In-block dtype probe: first wave checks 64 u64 words; int32 data read as
// u64 packs two values -> >= N almost surely. Result broadcast via LDS.
__device__ __forceinline__ int block_detect(const void* eidx, long long E,
                                            long long N, int* sflag) {
  bool ok = true;
  long long cap = E < 64 ? E : 64;
  if (threadIdx.x < cap)
    ok = ((const unsigned long long*)eidx)[threadIdx.x] < (unsigned long long)N;
  unsigned long long ball = __ballot(ok);
  if (threadIdx.x == 0) *sflag = (ball == ~0ULL) ? 1 : 0;
  __syncthreads();
  return *sflag;
}

// ---------------------------------------------------------------------------
// P1: per-bin edge counts; 4 per-wave LDS histograms to cut atomic conflicts.
__global__ __launch_bounds__(256) void k_p1(const void* eidx, long long E,
                                            int* __restrict__ binCnt,
                                            long long N, int nbin) {
  __shared__ int hist[4 * 512];
  __shared__ int sflag;
  for (int i = threadIdx.x; i < 4 * 512; i += 256) hist[i] = 0;
  int f = block_detect(eidx, E, N, &sflag);   // includes __syncthreads
  int* h = hist + 512 * (threadIdx.x >> 6);
  long long b0 = (long long)blockIdx.x * CHUNK;
#pragma unroll
  for (int i = 0; i < CHUNK / 256; ++i) {
    long long e = b0 + i * 256 + threadIdx.x;
    if (e < E) atomicAdd(&h[load_idx(eidx, E + e, f) >> 8], 1);
  }
  __syncthreads();
  for (int i = threadIdx.x; i < nbin; i += 256) {
    int s = hist[i] + hist[512 + i] + hist[1024 + i] + hist[1536 + i];
    if (s) atomicAdd(&binCnt[i], s);
  }
}

// exclusive scan of binCnt -> binBase, binCursor (nbin <= 512);
// spare threads zero the dummy rows (row N) of xw1b/xw2b.
__global__ __launch_bounds__(512) void k_scanbins(const int* __restrict__ binCnt,
                                                  int* __restrict__ binBase,
                                                  int* __restrict__ binCursor, int nbin,
                                                  unsigned* __restrict__ xw1b,
                                                  unsigned* __restrict__ xw2b, int N) {
  __shared__ int s[512];
  int t = threadIdx.x;
  if (t < HID_DIM / 2) xw1b[(size_t)N * (HID_DIM / 2) + t] = 0;
  else if (t < HID_DIM / 2 + OUT_DIM / 2)
    xw2b[(size_t)N * (OUT_DIM / 2) + (t - HID_DIM / 2)] = 0;
  int own = (t < nbin) ? binCnt[t] : 0;
  s[t] = own; __syncthreads();
  for (int o = 1; o < 512; o <<= 1) {
    int v = (t >= o) ? s[t - o] : 0;
    __syncthreads();
    s[t] += v;
    __syncthreads();
  }
  if (t < nbin) { int ex = s[t] - own; binBase[t] = ex; binCursor[t] = ex; }
}

// P2: scatter edges into bin-contiguous regions, packed {dstLocal<<17 | src}.
__global__ __launch_bounds__(256) void k_p2(const void* eidx, long long E,
                                            int* __restrict__ binCursor,
                                            unsigned* __restrict__ entry1,
                                            long long N, int nbin) {
  __shared__ int hist[512];
  __shared__ int basel[512];
  __shared__ int sflag;
  for (int i = threadIdx.x; i < nbin; i += 256) hist[i] = 0;
  int f = block_detect(eidx, E, N, &sflag);
  long long b0 = (long long)blockIdx.x * CHUNK;
#pragma unroll
  for (int i = 0; i < CHUNK / 256; ++i) {
    long long e = b0 + i * 256 + threadIdx.x;
    if (e < E) atomicAdd(&hist[load_idx(eidx, E + e, f) >> 8], 1);
  }
  __syncthreads();
  for (int i = threadIdx.x; i < nbin; i += 256) {
    int h = hist[i];
    basel[i] = h ? atomicAdd(&binCursor[i], h) : 0;
  }
  __syncthreads();
  for (int i = threadIdx.x; i < nbin; i += 256) hist[i] = 0;
  __syncthreads();
#pragma unroll
  for (int i = 0; i < CHUNK / 256; ++i) {
    long long e = b0 + i * 256 + threadIdx.x;
    if (e < E) {
      int r = load_idx(eidx, e, f);
      int c = load_idx(eidx, E + e, f);
      int bin = c >> 8;
      int rk = atomicAdd(&hist[bin], 1);
      entry1[basel[bin] + rk] = ((unsigned)(c & 255) << 17) | (unsigned)r;
    }
  }
}

// P3: one block per bin -> per-node CSR with 8-aligned runs (pad = dummy N).
__global__ __launch_bounds__(256) void k_p3(const unsigned* __restrict__ entry1,
                                            const int* __restrict__ binBase,
                                            const int* __restrict__ binCnt,
                                            int* __restrict__ entry2,
                                            int* __restrict__ base,
                                            int* __restrict__ cnt,
                                            float* __restrict__ dinv, int N) {
  __shared__ int hist[BPN];
  __shared__ int off[BPN];
  __shared__ int s[BPN];
  int t = threadIdx.x;
  int b = blockIdx.x;
  int lo = binBase[b];
  int hi = lo + binCnt[b];
  int pBB = ((lo + 7) & ~7) + 8 * BPN * b;   // padded, 8-aligned bin base
  int n0 = b * BPN;
  hist[t] = 0;
  __syncthreads();
  for (int i = lo + t; i < hi; i += 256)
    atomicAdd(&hist[entry1[i] >> 17], 1);
  __syncthreads();
  int own  = hist[t];
  int own8 = (own + 7) & ~7;
  s[t] = own8; __syncthreads();
  for (int o = 1; o < 256; o <<= 1) {
    int v = (t >= o) ? s[t - o] : 0;
    __syncthreads();
    s[t] += v;
    __syncthreads();
  }
  int node = n0 + t;
  int ex = pBB + (s[t] - own8);              // 8-aligned absolute slot
  if (node < N) {
    base[node] = ex;
    cnt[node]  = own;
    dinv[node] = rsqrtf((float)own + 1.0f);
    for (int q = own; q < own8; ++q) entry2[ex + q] = N;  // dummy pads
  }
  off[t] = ex;
  __syncthreads();
  for (int i = lo + t; i < hi; i += 256) {
    unsigned v = entry1[i];
    int pos = atomicAdd(&off[v >> 17], 1);
    entry2[pos] = (int)(v & 0x1FFFFu);
  }
}

// ---------------------------------------------------------------------------
// xw1b[r] = bf16( dinv[r] * (x[r] @ W1) )   packed 2-per-u32, [N][32] u32.
// 256 thr -> 64 rows x 64 cols, 4x4 per thread.
// x-tile (64x128 f32 = 32 KB) bulk-staged in LDS: deep coalesced prefetch of
// the HBM stream (the r4/r8/r11 variants were outstanding-miss bound), while
// 32 KB keeps 5 blocks/CU (the r9/r10 64 KB variants dropped to 2 blocks/CU).
// W1 from global: 16 lanes share each address, L2-hot, never the bottleneck.
// LDS reads: per half-wave only 2 distinct row addresses per ds_read_b128
// -> 2-way broadcast, conflict-free (m136; r9 measured 0 conflicts).
__global__ __launch_bounds__(256) void k_gemm1(const float* __restrict__ x,
                                               const float* __restrict__ W1,
                                               const float* __restrict__ dinv,
                                               unsigned* __restrict__ xw1b, int N) {
  __shared__ float xs[64 * IN_DIM];   // 32 KB, linear [row][128]
  {
    const int rbase = blockIdx.x * 64;
    float4* xd = (float4*)xs;
    const float4* xg = (const float4*)x;
#pragma unroll
    for (int j = 0; j < 8; ++j) {
      int i = threadIdx.x + 256 * j;        // 0..2047
      int r = i >> 5, c4 = i & 31;
      int rr = rbase + r; if (rr >= N) rr = N - 1;
      xd[i] = xg[(size_t)rr * 32 + c4];
    }
  }
  __syncthreads();

  const int rg = threadIdx.x >> 4;         // 0..15 row group
  const int jg = threadIdx.x & 15;         // 0..15 col group
  const int rl0 = rg * 4;                  // block-local row base
  const int j0  = jg * 4;

  float acc[4][4];
#pragma unroll
  for (int d = 0; d < 4; ++d)
#pragma unroll
    for (int q = 0; q < 4; ++q) acc[d][q] = 0.f;

  const float4* xs4 = (const float4*)xs;
#pragma unroll 4
  for (int k4 = 0; k4 < IN_DIM / 4; ++k4) {
    float4 wv[4];
#pragma unroll
    for (int q = 0; q < 4; ++q)
      wv[q] = *(const float4*)(W1 + (4 * k4 + q) * HID_DIM + j0);
    float4 xv[4];
#pragma unroll
    for (int d = 0; d < 4; ++d)
      xv[d] = xs4[(rl0 + d) * 32 + k4];
#pragma unroll
    for (int d = 0; d < 4; ++d) {
      acc[d][0] += xv[d].x * wv[0].x + xv[d].y * wv[1].x + xv[d].z * wv[2].x + xv[d].w * wv[3].x;
      acc[d][1] += xv[d].x * wv[0].y + xv[d].y * wv[1].y + xv[d].z * wv[2].y + xv[d].w * wv[3].y;
      acc[d][2] += xv[d].x * wv[0].z + xv[d].y * wv[1].z + xv[d].z * wv[2].z + xv[d].w * wv[3].z;
      acc[d][3] += xv[d].x * wv[0].w + xv[d].y * wv[1].w + xv[d].z * wv[2].w + xv[d].w * wv[3].w;
    }
  }

  const int rbase = blockIdx.x * 64;
#pragma unroll
  for (int d = 0; d < 4; ++d) {
    int r = rbase + rl0 + d;
    if (r < N) {
      float dv = dinv[r];
      uint2 pv;
      pv.x = pack_bf16(dv * acc[d][0], dv * acc[d][1]);
      pv.y = pack_bf16(dv * acc[d][2], dv * acc[d][3]);
      *(uint2*)(xw1b + (size_t)r * (HID_DIM / 2) + 2 * jg) = pv;
    }
  }
}

// ---------------------------------------------------------------------------
// gather layer 1 + relu + GEMM2, wave-self-contained; 8-deep payload MLP.
// 16 nodes/block; each wave owns 4 nodes (16 lanes/node, dwordx2 payloads).
__global__ __launch_bounds__(256) void k_gather1(const int* __restrict__ entry,
                                                 const int* __restrict__ base,
                                                 const int* __restrict__ cnt,
                                                 const float* __restrict__ dinv,
                                                 const uint2* __restrict__ xw1b2,
                                                 const float* __restrict__ b1,
                                                 const float* __restrict__ W2,
                                                 unsigned* __restrict__ xw2b, int N) {
  __shared__ float w2s[HID_DIM * OUT_DIM];  // 8 KB
  __shared__ float hs[16][68];              // row stride 272 B (16B-aligned)
  __shared__ float dvs[16];
  for (int i = threadIdx.x; i < HID_DIM * OUT_DIM; i += 256) w2s[i] = W2[i];
  __syncthreads();   // w2s ready; only barrier in the kernel

  const int wv   = threadIdx.x >> 6;   // wave 0..3
  const int ln   = threadIdx.x & 63;
  const int slot = wv * 4 + (ln >> 4); // node slot 0..15 (4 per wave)
  const int lane = ln & 15;            // lane owns dims 4*lane..4*lane+3
  const int node = blockIdx.x * 16 + slot;

  if (node < N) {
    int st = base[node];
    int it = (cnt[node] + 7) >> 3;
    float ax[4], ay[4], az[4], aw[4];
#pragma unroll
    for (int q = 0; q < 4; ++q) { ax[q] = ay[q] = az[q] = aw[q] = 0.f; }
    for (int i = 0; i < it; ++i) {
      int4 ea = *(const int4*)(entry + st + 8 * i);
      int4 eb = *(const int4*)(entry + st + 8 * i + 4);
      uint2 v0 = xw1b2[(size_t)ea.x * 16 + lane];
      uint2 v1 = xw1b2[(size_t)ea.y * 16 + lane];
      uint2 v2 = xw1b2[(size_t)ea.z * 16 + lane];
      uint2 v3 = xw1b2[(size_t)ea.w * 16 + lane];
      uint2 v4 = xw1b2[(size_t)eb.x * 16 + lane];
      uint2 v5 = xw1b2[(size_t)eb.y * 16 + lane];
      uint2 v6 = xw1b2[(size_t)eb.z * 16 + lane];
      uint2 v7 = xw1b2[(size_t)eb.w * 16 + lane];
      ax[0] += bf_lo(v0.x) + bf_lo(v4.x); ay[0] += bf_hi(v0.x) + bf_hi(v4.x);
      az[0] += bf_lo(v0.y) + bf_lo(v4.y); aw[0] += bf_hi(v0.y) + bf_hi(v4.y);
      ax[1] += bf_lo(v1.x) + bf_lo(v5.x); ay[1] += bf_hi(v1.x) + bf_hi(v5.x);
      az[1] += bf_lo(v1.y) + bf_lo(v5.y); aw[1] += bf_hi(v1.y) + bf_hi(v5.y);
      ax[2] += bf_lo(v2.x) + bf_lo(v6.x); ay[2] += bf_hi(v2.x) + bf_hi(v6.x);
      az[2] += bf_lo(v2.y) + bf_lo(v6.y); aw[2] += bf_hi(v2.y) + bf_hi(v6.y);
      ax[3] += bf_lo(v3.x) + bf_lo(v7.x); ay[3] += bf_hi(v3.x) + bf_hi(v7.x);
      az[3] += bf_lo(v3.y) + bf_lo(v7.y); aw[3] += bf_hi(v3.y) + bf_hi(v7.y);
    }
    uint2 vs = xw1b2[(size_t)node * 16 + lane];  // self-loop
    float dv = dinv[node];
    float4 bb = *(const float4*)(b1 + 4 * lane);
    float h0 = dv * ((ax[0] + ax[1]) + (ax[2] + ax[3]) + bf_lo(vs.x)) + bb.x;
    float h1 = dv * ((ay[0] + ay[1]) + (ay[2] + ay[3]) + bf_hi(vs.x)) + bb.y;
    float h2 = dv * ((az[0] + az[1]) + (az[2] + az[3]) + bf_lo(vs.y)) + bb.z;
    float h3 = dv * ((aw[0] + aw[1]) + (aw[2] + aw[3]) + bf_hi(vs.y)) + bb.w;
    float4 hv;
    hv.x = h0 > 0.f ? h0 : 0.f;
    hv.y = h1 > 0.f ? h1 : 0.f;
    hv.z = h2 > 0.f ? h2 : 0.f;
    hv.w = h3 > 0.f ? h3 : 0.f;
    *(float4*)(&hs[slot][4 * lane]) = hv;
    if (lane == 0) dvs[slot] = dv;
  }
  __builtin_amdgcn_wave_barrier();  // keep compiler from reordering DS ops

  if (node < N) {
    float acc0 = 0.f, acc1 = 0.f;
#pragma unroll
    for (int jj = 0; jj < HID_DIM; ++jj) {
      float hv = hs[slot][jj];
      float2 w = *(const float2*)(w2s + jj * OUT_DIM + 2 * lane);
      acc0 += hv * w.x;
      acc1 += hv * w.y;
    }
    float dv = dvs[slot];
    xw2b[(size_t)node * (OUT_DIM / 2) + lane] = pack_bf16(dv * acc0, dv * acc1);
  }
}

// ---------------------------------------------------------------------------
// gather layer 2 + relu -> d_out. 32 nodes/block, 8 lanes/node, 8-deep MLP.
__global__ __launch_bounds__(256) void k_gather2(const int* __restrict__ entry,
                                                 const int* __restrict__ base,
                                                 const int* __restrict__ cnt,
                                                 const float* __restrict__ dinv,
                                                 const uint2* __restrict__ xw2b2,
                                                 const float* __restrict__ b2,
                                                 float* __restrict__ out, int N) {
  const int nl   = threadIdx.x >> 3;   // 0..31
  const int lane = threadIdx.x & 7;    // lane owns dims 4*lane..4*lane+3
  const int node = blockIdx.x * 32 + nl;
  if (node >= N) return;
  int st = base[node];
  int it = (cnt[node] + 7) >> 3;
  float ax[4], ay[4], az[4], aw[4];
#pragma unroll
  for (int q = 0; q < 4; ++q) { ax[q] = ay[q] = az[q] = aw[q] = 0.f; }
  for (int i = 0; i < it; ++i) {
    int4 ea = *(const int4*)(entry + st + 8 * i);
    int4 eb = *(const int4*)(entry + st + 8 * i + 4);
    uint2 v0 = xw2b2[(size_t)ea.x * 8 + lane];
    uint2 v1 = xw2b2[(size_t)ea.y * 8 + lane];
    uint2 v2 = xw2b2[(size_t)ea.z * 8 + lane];
    uint2 v3 = xw2b2[(size_t)ea.w * 8 + lane];
    uint2 v4 = xw2b2[(size_t)eb.x * 8 + lane];
    uint2 v5 = xw2b2[(size_t)eb.y * 8 + lane];
    uint2 v6 = xw2b2[(size_t)eb.z * 8 + lane];
    uint2 v7 = xw2b2[(size_t)eb.w * 8 + lane];
    ax[0] += bf_lo(v0.x) + bf_lo(v4.x); ay[0] += bf_hi(v0.x) + bf_hi(v4.x);
    az[0] += bf_lo(v0.y) + bf_lo(v4.y); aw[0] += bf_hi(v0.y) + bf_hi(v4.y);
    ax[1] += bf_lo(v1.x) + bf_lo(v5.x); ay[1] += bf_hi(v1.x) + bf_hi(v5.x);
    az[1] += bf_lo(v1.y) + bf_lo(v5.y); aw[1] += bf_hi(v1.y) + bf_hi(v5.y);
    ax[2] += bf_lo(v2.x) + bf_lo(v6.x); ay[2] += bf_hi(v2.x) + bf_hi(v6.x);
    az[2] += bf_lo(v2.y) + bf_lo(v6.y); aw[2] += bf_hi(v2.y) + bf_hi(v6.y);
    ax[3] += bf_lo(v3.x) + bf_lo(v7.x); ay[3] += bf_hi(v3.x) + bf_hi(v7.x);
    az[3] += bf_lo(v3.y) + bf_lo(v7.y); aw[3] += bf_hi(v3.y) + bf_hi(v7.y);
  }
  uint2 vs = xw2b2[(size_t)node * 8 + lane];  // self-loop
  float dv = dinv[node];
  float4 bb = *(const float4*)(b2 + 4 * lane);
  float v0 = dv * ((ax[0] + ax[1]) + (ax[2] + ax[3]) + bf_lo(vs.x)) + bb.x;
  float v1 = dv * ((ay[0] + ay[1]) + (ay[2] + ay[3]) + bf_hi(vs.x)) + bb.y;
  float v2 = dv * ((az[0] + az[1]) + (az[2] + az[3]) + bf_lo(vs.y)) + bb.z;
  float v3 = dv * ((aw[0] + aw[1]) + (aw[2] + aw[3]) + bf_hi(vs.y)) + bb.w;
  float4 res;
  res.x = v0 > 0.f ? v0 : 0.f;
  res.y = v1 > 0.f ? v1 : 0.f;
  res.z = v2 > 0.f ? v2 : 0.f;
  res.w = v3 > 0.f ? v3 : 0.f;
  *(float4*)(out + (size_t)node * OUT_DIM + 4 * lane) = res;
}

// ---------------------------------------------------------------------------
static inline size_t align256(size_t x) { return (x + 255) & ~(size_t)255; }

extern "C" void kernel_launch(void* const* d_in, const int* in_sizes, int n_in,
                              void* d_out, int out_size, void* d_ws, size_t ws_size,
                              hipStream_t stream) {
  const float* x   = (const float*)d_in[0];
  const float* W1  = (const float*)d_in[1];
  const float* b1  = (const float*)d_in[2];
  const float* W2  = (const float*)d_in[3];
  const float* b2  = (const float*)d_in[4];
  const void*  eidx = d_in[5];

  const int  N = in_sizes[0] / IN_DIM;             // 100000 (< 2^17 for packing)
  const long long E = (long long)in_sizes[5] / 2;  // 1600000
  const int  nbin = (N + BPN - 1) / BPN;           // 391 (<= 512)
  const int  np   = (int)((E + CHUNK - 1) / CHUNK);
  const size_t e2cap = (size_t)E + (size_t)8 * BPN * nbin + 64;

  char* ws = (char*)d_ws;
  size_t off = 0;
  int*      cnt       = (int*)(ws + off);      off += align256((size_t)N * 4);
  float*    dinv      = (float*)(ws + off);    off += align256((size_t)N * 4);
  int*      base      = (int*)(ws + off);      off += align256((size_t)N * 4);
  int*      binCnt    = (int*)(ws + off);      off += align256(512 * 4);
  int*      binBase   = (int*)(ws + off);      off += align256(512 * 4);
  int*      binCursor = (int*)(ws + off);      off += align256(512 * 4);
  unsigned* entry1    = (unsigned*)(ws + off); off += align256((size_t)E * 4);
  int*      entry2    = (int*)(ws + off);      off += align256(e2cap * 4);
  unsigned* xw1b      = (unsigned*)(ws + off); off += align256((size_t)(N + 1) * (HID_DIM / 2) * 4);
  unsigned* xw2b      = (unsigned*)(ws + off); off += align256((size_t)(N + 1) * (OUT_DIM / 2) * 4);
  float*    outf      = (float*)d_out;

  hipMemsetAsync(binCnt, 0, 512 * 4, stream);

  k_p1<<<np, 256, 0, stream>>>(eidx, E, binCnt, (long long)N, nbin);
  k_scanbins<<<1, 512, 0, stream>>>(binCnt, binBase, binCursor, nbin, xw1b, xw2b, N);
  k_p2<<<np, 256, 0, stream>>>(eidx, E, binCursor, entry1, (long long)N, nbin);
  k_p3<<<nbin, 256, 0, stream>>>(entry1, binBase, binCnt, entry2, base, cnt, dinv, N);

  k_gemm1<<<(N + 63) / 64, 256, 0, stream>>>(x, W1, dinv, xw1b, N);

  k_gather1<<<(N + 15) / 16, 256, 0, stream>>>(entry2, base, cnt, dinv,
                                               (const uint2*)xw1b, b1, W2, xw2b, N);

  k_gather2<<<(N + 31) / 32, 256, 0, stream>>>(entry2, base, cnt, dinv,
                                               (const uint2*)xw2b, b2, outf, N);
}

// Round 13
// 140.818 us; speedup vs baseline: 1.2742x; 1.1457x over previous
//
#include <hip/hip_runtime.h>

#define IN_DIM  128
#define HID_DIM 64
#define OUT_DIM 32
#define BPN   256     // nodes per destination bin (dstLocal fits 8 bits)
#define CHUNK 4096    // edges per partition block (256 thr x 16)

typedef __attribute__((ext_vector_type(8))) short bf16x8;
typedef __attribute__((ext_vector_type(4))) float f32x4;

// ---------------------------------------------------------------------------
// pack two f32 -> (bf16,bf16) in one u32, round-to-nearest-even
__device__ __forceinline__ unsigned pack_bf16(float a, float b) {
  unsigned ua = __float_as_uint(a), ub = __float_as_uint(b);
  ua += 0x7FFFu + ((ua >> 16) & 1u);
  ub += 0x7FFFu + ((ub >> 16) & 1u);
  return (ua >> 16) | (ub & 0xFFFF0000u);
}
__device__ __forceinline__ float bf_lo(unsigned v) { return __uint_as_float(v << 16); }
__device__ __forceinline__ float bf_hi(unsigned v) { return __uint_as_float(v & 0xFFFF0000u); }

__device__ __forceinline__ int load_idx(const void* p, long long i, int is64) {
  return is64 ? (int)((const long long*)p)[i] : ((const int*)p)[i];
}

// In-block dtype probe: first wave checks 64 u64 words; int32 data read as
// u64 packs two values -> >= N almost surely. Result broadcast via LDS.
__device__ __forceinline__ int block_detect(const void* eidx, long long E,
                                            long long N, int* sflag) {
  bool ok = true;
  long long cap = E < 64 ? E : 64;
  if (threadIdx.x < cap)
    ok = ((const unsigned long long*)eidx)[threadIdx.x] < (unsigned long long)N;
  unsigned long long ball = __ballot(ok);
  if (threadIdx.x == 0) *sflag = (ball == ~0ULL) ? 1 : 0;
  __syncthreads();
  return *sflag;
}

// ---------------------------------------------------------------------------
// P1: per-bin edge counts; 4 per-wave LDS histograms to cut atomic conflicts.
__global__ __launch_bounds__(256) void k_p1(const void* eidx, long long E,
                                            int* __restrict__ binCnt,
                                            long long N, int nbin) {
  __shared__ int hist[4 * 512];
  __shared__ int sflag;
  for (int i = threadIdx.x; i < 4 * 512; i += 256) hist[i] = 0;
  int f = block_detect(eidx, E, N, &sflag);   // includes __syncthreads
  int* h = hist + 512 * (threadIdx.x >> 6);
  long long b0 = (long long)blockIdx.x * CHUNK;
#pragma unroll
  for (int i = 0; i < CHUNK / 256; ++i) {
    long long e = b0 + i * 256 + threadIdx.x;
    if (e < E) atomicAdd(&h[load_idx(eidx, E + e, f) >> 8], 1);
  }
  __syncthreads();
  for (int i = threadIdx.x; i < nbin; i += 256) {
    int s = hist[i] + hist[512 + i] + hist[1024 + i] + hist[1536 + i];
    if (s) atomicAdd(&binCnt[i], s);
  }
}

// exclusive scan of binCnt -> binBase, binCursor (nbin <= 512);
// also: W1 -> bf16 transposed [j][k] for MFMA B-fragments, and zero the
// dummy rows (row N) of xw1b/xw2b.
__global__ __launch_bounds__(512) void k_scanbins(const int* __restrict__ binCnt,
                                                  int* __restrict__ binBase,
                                                  int* __restrict__ binCursor, int nbin,
                                                  const float* __restrict__ W1,
                                                  unsigned short* __restrict__ w1t,
                                                  unsigned* __restrict__ xw1b,
                                                  unsigned* __restrict__ xw2b, int N) {
  __shared__ int s[512];
  int t = threadIdx.x;
  if (t < HID_DIM / 2) xw1b[(size_t)N * (HID_DIM / 2) + t] = 0;
  else if (t < HID_DIM / 2 + OUT_DIM / 2)
    xw2b[(size_t)N * (OUT_DIM / 2) + (t - HID_DIM / 2)] = 0;
  // W1T[j][k] = bf16(W1[k][j]);  64*128 = 8192 elements, 16 per thread
  for (int i = t; i < HID_DIM * IN_DIM; i += 512) {
    int j = i >> 7, k = i & 127;
    w1t[i] = (unsigned short)(pack_bf16(W1[k * HID_DIM + j], 0.f) & 0xFFFFu);
  }
  int own = (t < nbin) ? binCnt[t] : 0;
  s[t] = own; __syncthreads();
  for (int o = 1; o < 512; o <<= 1) {
    int v = (t >= o) ? s[t - o] : 0;
    __syncthreads();
    s[t] += v;
    __syncthreads();
  }
  if (t < nbin) { int ex = s[t] - own; binBase[t] = ex; binCursor[t] = ex; }
}

// P2: scatter edges into bin-contiguous regions, packed {dstLocal<<17 | src}.
__global__ __launch_bounds__(256) void k_p2(const void* eidx, long long E,
                                            int* __restrict__ binCursor,
                                            unsigned* __restrict__ entry1,
                                            long long N, int nbin) {
  __shared__ int hist[512];
  __shared__ int basel[512];
  __shared__ int sflag;
  for (int i = threadIdx.x; i < nbin; i += 256) hist[i] = 0;
  int f = block_detect(eidx, E, N, &sflag);
  long long b0 = (long long)blockIdx.x * CHUNK;
#pragma unroll
  for (int i = 0; i < CHUNK / 256; ++i) {
    long long e = b0 + i * 256 + threadIdx.x;
    if (e < E) atomicAdd(&hist[load_idx(eidx, E + e, f) >> 8], 1);
  }
  __syncthreads();
  for (int i = threadIdx.x; i < nbin; i += 256) {
    int h = hist[i];
    basel[i] = h ? atomicAdd(&binCursor[i], h) : 0;
  }
  __syncthreads();
  for (int i = threadIdx.x; i < nbin; i += 256) hist[i] = 0;
  __syncthreads();
#pragma unroll
  for (int i = 0; i < CHUNK / 256; ++i) {
    long long e = b0 + i * 256 + threadIdx.x;
    if (e < E) {
      int r = load_idx(eidx, e, f);
      int c = load_idx(eidx, E + e, f);
      int bin = c >> 8;
      int rk = atomicAdd(&hist[bin], 1);
      entry1[basel[bin] + rk] = ((unsigned)(c & 255) << 17) | (unsigned)r;
    }
  }
}

// P3: one block per bin -> per-node CSR with 8-aligned runs (pad = dummy N).
__global__ __launch_bounds__(256) void k_p3(const unsigned* __restrict__ entry1,
                                            const int* __restrict__ binBase,
                                            const int* __restrict__ binCnt,
                                            int* __restrict__ entry2,
                                            int* __restrict__ base,
                                            int* __restrict__ cnt,
                                            float* __restrict__ dinv, int N) {
  __shared__ int hist[BPN];
  __shared__ int off[BPN];
  __shared__ int s[BPN];
  int t = threadIdx.x;
  int b = blockIdx.x;
  int lo = binBase[b];
  int hi = lo + binCnt[b];
  int pBB = ((lo + 7) & ~7) + 8 * BPN * b;   // padded, 8-aligned bin base
  int n0 = b * BPN;
  hist[t] = 0;
  __syncthreads();
  for (int i = lo + t; i < hi; i += 256)
    atomicAdd(&hist[entry1[i] >> 17], 1);
  __syncthreads();
  int own  = hist[t];
  int own8 = (own + 7) & ~7;
  s[t] = own8; __syncthreads();
  for (int o = 1; o < 256; o <<= 1) {
    int v = (t >= o) ? s[t - o] : 0;
    __syncthreads();
    s[t] += v;
    __syncthreads();
  }
  int node = n0 + t;
  int ex = pBB + (s[t] - own8);              // 8-aligned absolute slot
  if (node < N) {
    base[node] = ex;
    cnt[node]  = own;
    dinv[node] = rsqrtf((float)own + 1.0f);
    for (int q = own; q < own8; ++q) entry2[ex + q] = N;  // dummy pads
  }
  off[t] = ex;
  __syncthreads();
  for (int i = lo + t; i < hi; i += 256) {
    unsigned v = entry1[i];
    int pos = atomicAdd(&off[v >> 17], 1);
    entry2[pos] = (int)(v & 0x1FFFFu);
  }
}

// ---------------------------------------------------------------------------
// xw1b[r] = bf16( dinv[r] * (x[r] @ W1) )  via MFMA bf16 (f32 accumulate).
// Rationale (r4/r8/r11/r12 post-mortems): every f32-FMA structure floors at
// ~46us on operand bytes/FLOP. MFMA reads 2 b128 frags per 16x16x32 tile.
// Block: 256 thr = 4 waves; 64 rows x 64 cols, K=128. Per wave: rows wv*16..+15,
// 4 col-tiles x 4 K-steps = 16 MFMA. LDS: x-tile bf16 [64][128] + W1T bf16
// [64][128], both with 16B-chunk XOR swizzle (chunk ^= row&7) -> each
// quarter-wave's 16 row-addresses cover all 32 banks (2-way max, free m136).
__global__ __launch_bounds__(256) void k_gemm1(const float* __restrict__ x,
                                               const unsigned short* __restrict__ w1t,
                                               const float* __restrict__ dinv,
                                               unsigned* __restrict__ xw1b, int N) {
  __shared__ unsigned short xs[64 * IN_DIM];   // 16 KB, swizzled
  __shared__ unsigned short wt[64 * IN_DIM];   // 16 KB, swizzled
  const int rbase = blockIdx.x * 64;

  // stage x (f32 -> bf16): flat float4 index f: row=f>>5, c4=f&31 (k=4*c4..)
  {
    const float4* xg = (const float4*)x;
#pragma unroll
    for (int j = 0; j < 8; ++j) {
      int fIdx = threadIdx.x + 256 * j;          // 0..2047
      int r = fIdx >> 5, c4 = fIdx & 31;
      int rr = rbase + r; if (rr >= N) rr = N - 1;
      float4 v = xg[(size_t)rr * 32 + c4];
      uint2 pv = make_uint2(pack_bf16(v.x, v.y), pack_bf16(v.z, v.w));
      int chunk = (c4 >> 1) ^ (r & 7);
      *(uint2*)((char*)xs + r * 256 + chunk * 16 + (c4 & 1) * 8) = pv;
    }
  }
  // stage W1T (already bf16): flat uint2 index f: row=f>>5, q=f&31
  {
    const uint2* wg = (const uint2*)w1t;
#pragma unroll
    for (int j = 0; j < 8; ++j) {
      int fIdx = threadIdx.x + 256 * j;          // 0..2047
      int r = fIdx >> 5, q = fIdx & 31;
      uint2 v = wg[fIdx];
      int chunk = (q >> 1) ^ (r & 7);
      *(uint2*)((char*)wt + r * 256 + chunk * 16 + (q & 1) * 8) = v;
    }
  }
  __syncthreads();

  const int wv = threadIdx.x >> 6;
  const int l  = threadIdx.x & 63;
  const int lo16 = l & 15;
  const int hi4  = l >> 4;          // 0..3

  // A fragments: lane holds x-row (wv*16 + lo16), k = ks*32 + hi4*8 .. +7
  bf16x8 a[4];
#pragma unroll
  for (int ks = 0; ks < 4; ++ks) {
    int row = wv * 16 + lo16;
    int chunk = (ks * 4 + hi4) ^ (row & 7);
    a[ks] = *(const bf16x8*)((const char*)xs + row * 256 + chunk * 16);
  }

  f32x4 acc[4];
#pragma unroll
  for (int ct = 0; ct < 4; ++ct) {
    f32x4 c = {0.f, 0.f, 0.f, 0.f};
#pragma unroll
    for (int ks = 0; ks < 4; ++ks) {
      int col = ct * 16 + lo16;
      int chunk = (ks * 4 + hi4) ^ (col & 7);
      bf16x8 b = *(const bf16x8*)((const char*)wt + col * 256 + chunk * 16);
      c = __builtin_amdgcn_mfma_f32_16x16x32_bf16(a[ks], b, c, 0, 0, 0);
    }
    acc[ct] = c;
  }

  // epilogue: D[row=(l>>4)*4+i][col=l&15] (m89). Pack col pairs via shfl_xor.
  float dvr[4];
#pragma unroll
  for (int i = 0; i < 4; ++i) {
    int row = rbase + wv * 16 + hi4 * 4 + i;
    dvr[i] = (row < N) ? dinv[row] : 0.f;
  }
#pragma unroll
  for (int ct = 0; ct < 4; ++ct) {
#pragma unroll
    for (int i = 0; i < 4; ++i) {
      float v = dvr[i] * acc[ct][i];
      float vp = __shfl_xor(v, 1);
      int row = rbase + wv * 16 + hi4 * 4 + i;
      if ((l & 1) == 0 && row < N) {
        int j = ct * 16 + lo16;          // even
        xw1b[(size_t)row * (HID_DIM / 2) + (j >> 1)] = pack_bf16(v, vp);
      }
    }
  }
}

// ---------------------------------------------------------------------------
// gather layer 1 + relu + GEMM2, wave-self-contained; 8-deep payload MLP.
// 16 nodes/block; each wave owns 4 nodes (16 lanes/node, dwordx2 payloads).
__global__ __launch_bounds__(256) void k_gather1(const int* __restrict__ entry,
                                                 const int* __restrict__ base,
                                                 const int* __restrict__ cnt,
                                                 const float* __restrict__ dinv,
                                                 const uint2* __restrict__ xw1b2,
                                                 const float* __restrict__ b1,
                                                 const float* __restrict__ W2,
                                                 unsigned* __restrict__ xw2b, int N) {
  __shared__ float w2s[HID_DIM * OUT_DIM];  // 8 KB
  __shared__ float hs[16][68];              // row stride 272 B (16B-aligned)
  __shared__ float dvs[16];
  for (int i = threadIdx.x; i < HID_DIM * OUT_DIM; i += 256) w2s[i] = W2[i];
  __syncthreads();   // w2s ready; only barrier in the kernel

  const int wv   = threadIdx.x >> 6;   // wave 0..3
  const int ln   = threadIdx.x & 63;
  const int slot = wv * 4 + (ln >> 4); // node slot 0..15 (4 per wave)
  const int lane = ln & 15;            // lane owns dims 4*lane..4*lane+3
  const int node = blockIdx.x * 16 + slot;

  if (node < N) {
    int st = base[node];
    int it = (cnt[node] + 7) >> 3;
    float ax[4], ay[4], az[4], aw[4];
#pragma unroll
    for (int q = 0; q < 4; ++q) { ax[q] = ay[q] = az[q] = aw[q] = 0.f; }
    for (int i = 0; i < it; ++i) {
      int4 ea = *(const int4*)(entry + st + 8 * i);
      int4 eb = *(const int4*)(entry + st + 8 * i + 4);
      uint2 v0 = xw1b2[(size_t)ea.x * 16 + lane];
      uint2 v1 = xw1b2[(size_t)ea.y * 16 + lane];
      uint2 v2 = xw1b2[(size_t)ea.z * 16 + lane];
      uint2 v3 = xw1b2[(size_t)ea.w * 16 + lane];
      uint2 v4 = xw1b2[(size_t)eb.x * 16 + lane];
      uint2 v5 = xw1b2[(size_t)eb.y * 16 + lane];
      uint2 v6 = xw1b2[(size_t)eb.z * 16 + lane];
      uint2 v7 = xw1b2[(size_t)eb.w * 16 + lane];
      ax[0] += bf_lo(v0.x) + bf_lo(v4.x); ay[0] += bf_hi(v0.x) + bf_hi(v4.x);
      az[0] += bf_lo(v0.y) + bf_lo(v4.y); aw[0] += bf_hi(v0.y) + bf_hi(v4.y);
      ax[1] += bf_lo(v1.x) + bf_lo(v5.x); ay[1] += bf_hi(v1.x) + bf_hi(v5.x);
      az[1] += bf_lo(v1.y) + bf_lo(v5.y); aw[1] += bf_hi(v1.y) + bf_hi(v5.y);
      ax[2] += bf_lo(v2.x) + bf_lo(v6.x); ay[2] += bf_hi(v2.x) + bf_hi(v6.x);
      az[2] += bf_lo(v2.y) + bf_lo(v6.y); aw[2] += bf_hi(v2.y) + bf_hi(v6.y);
      ax[3] += bf_lo(v3.x) + bf_lo(v7.x); ay[3] += bf_hi(v3.x) + bf_hi(v7.x);
      az[3] += bf_lo(v3.y) + bf_lo(v7.y); aw[3] += bf_hi(v3.y) + bf_hi(v7.y);
    }
    uint2 vs = xw1b2[(size_t)node * 16 + lane];  // self-loop
    float dv = dinv[node];
    float4 bb = *(const float4*)(b1 + 4 * lane);
    float h0 = dv * ((ax[0] + ax[1]) + (ax[2] + ax[3]) + bf_lo(vs.x)) + bb.x;
    float h1 = dv * ((ay[0] + ay[1]) + (ay[2] + ay[3]) + bf_hi(vs.x)) + bb.y;
    float h2 = dv * ((az[0] + az[1]) + (az[2] + az[3]) + bf_lo(vs.y)) + bb.z;
    float h3 = dv * ((aw[0] + aw[1]) + (aw[2] + aw[3]) + bf_hi(vs.y)) + bb.w;
    float4 hv;
    hv.x = h0 > 0.f ? h0 : 0.f;
    hv.y = h1 > 0.f ? h1 : 0.f;
    hv.z = h2 > 0.f ? h2 : 0.f;
    hv.w = h3 > 0.f ? h3 : 0.f;
    *(float4*)(&hs[slot][4 * lane]) = hv;
    if (lane == 0) dvs[slot] = dv;
  }
  __builtin_amdgcn_wave_barrier();  // keep compiler from reordering DS ops

  if (node < N) {
    float acc0 = 0.f, acc1 = 0.f;
#pragma unroll
    for (int jj = 0; jj < HID_DIM; ++jj) {
      float hv = hs[slot][jj];
      float2 w = *(const float2*)(w2s + jj * OUT_DIM + 2 * lane);
      acc0 += hv * w.x;
      acc1 += hv * w.y;
    }
    float dv = dvs[slot];
    xw2b[(size_t)node * (OUT_DIM / 2) + lane] = pack_bf16(dv * acc0, dv * acc1);
  }
}

// ---------------------------------------------------------------------------
// gather layer 2 + relu -> d_out. 32 nodes/block, 8 lanes/node, 8-deep MLP.
__global__ __launch_bounds__(256) void k_gather2(const int* __restrict__ entry,
                                                 const int* __restrict__ base,
                                                 const int* __restrict__ cnt,
                                                 const float* __restrict__ dinv,
                                                 const uint2* __restrict__ xw2b2,
                                                 const float* __restrict__ b2,
                                                 float* __restrict__ out, int N) {
  const int nl   = threadIdx.x >> 3;   // 0..31
  const int lane = threadIdx.x & 7;    // lane owns dims 4*lane..4*lane+3
  const int node = blockIdx.x * 32 + nl;
  if (node >= N) return;
  int st = base[node];
  int it = (cnt[node] + 7) >> 3;
  float ax[4], ay[4], az[4], aw[4];
#pragma unroll
  for (int q = 0; q < 4; ++q) { ax[q] = ay[q] = az[q] = aw[q] = 0.f; }
  for (int i = 0; i < it; ++i) {
    int4 ea = *(const int4*)(entry + st + 8 * i);
    int4 eb = *(const int4*)(entry + st + 8 * i + 4);
    uint2 v0 = xw2b2[(size_t)ea.x * 8 + lane];
    uint2 v1 = xw2b2[(size_t)ea.y * 8 + lane];
    uint2 v2 = xw2b2[(size_t)ea.z * 8 + lane];
    uint2 v3 = xw2b2[(size_t)ea.w * 8 + lane];
    uint2 v4 = xw2b2[(size_t)eb.x * 8 + lane];
    uint2 v5 = xw2b2[(size_t)eb.y * 8 + lane];
    uint2 v6 = xw2b2[(size_t)eb.z * 8 + lane];
    uint2 v7 = xw2b2[(size_t)eb.w * 8 + lane];
    ax[0] += bf_lo(v0.x) + bf_lo(v4.x); ay[0] += bf_hi(v0.x) + bf_hi(v4.x);
    az[0] += bf_lo(v0.y) + bf_lo(v4.y); aw[0] += bf_hi(v0.y) + bf_hi(v4.y);
    ax[1] += bf_lo(v1.x) + bf_lo(v5.x); ay[1] += bf_hi(v1.x) + bf_hi(v5.x);
    az[1] += bf_lo(v1.y) + bf_lo(v5.y); aw[1] += bf_hi(v1.y) + bf_hi(v5.y);
    ax[2] += bf_lo(v2.x) + bf_lo(v6.x); ay[2] += bf_hi(v2.x) + bf_hi(v6.x);
    az[2] += bf_lo(v2.y) + bf_lo(v6.y); aw[2] += bf_hi(v2.y) + bf_hi(v6.y);
    ax[3] += bf_lo(v3.x) + bf_lo(v7.x); ay[3] += bf_hi(v3.x) + bf_hi(v7.x);
    az[3] += bf_lo(v3.y) + bf_lo(v7.y); aw[3] += bf_hi(v3.y) + bf_hi(v7.y);
  }
  uint2 vs = xw2b2[(size_t)node * 8 + lane];  // self-loop
  float dv = dinv[node];
  float4 bb = *(const float4*)(b2 + 4 * lane);
  float v0 = dv * ((ax[0] + ax[1]) + (ax[2] + ax[3]) + bf_lo(vs.x)) + bb.x;
  float v1 = dv * ((ay[0] + ay[1]) + (ay[2] + ay[3]) + bf_hi(vs.x)) + bb.y;
  float v2 = dv * ((az[0] + az[1]) + (az[2] + az[3]) + bf_lo(vs.y)) + bb.z;
  float v3 = dv * ((aw[0] + aw[1]) + (aw[2] + aw[3]) + bf_hi(vs.y)) + bb.w;
  float4 res;
  res.x = v0 > 0.f ? v0 : 0.f;
  res.y = v1 > 0.f ? v1 : 0.f;
  res.z = v2 > 0.f ? v2 : 0.f;
  res.w = v3 > 0.f ? v3 : 0.f;
  *(float4*)(out + (size_t)node * OUT_DIM + 4 * lane) = res;
}

// ---------------------------------------------------------------------------
static inline size_t align256(size_t x) { return (x + 255) & ~(size_t)255; }

extern "C" void kernel_launch(void* const* d_in, const int* in_sizes, int n_in,
                              void* d_out, int out_size, void* d_ws, size_t ws_size,
                              hipStream_t stream) {
  const float* x   = (const float*)d_in[0];
  const float* W1  = (const float*)d_in[1];
  const float* b1  = (const float*)d_in[2];
  const float* W2  = (const float*)d_in[3];
  const float* b2  = (const float*)d_in[4];
  const void*  eidx = d_in[5];

  const int  N = in_sizes[0] / IN_DIM;             // 100000 (< 2^17 for packing)
  const long long E = (long long)in_sizes[5] / 2;  // 1600000
  const int  nbin = (N + BPN - 1) / BPN;           // 391 (<= 512)
  const int  np   = (int)((E + CHUNK - 1) / CHUNK);
  const size_t e2cap = (size_t)E + (size_t)8 * BPN * nbin + 64;

  char* ws = (char*)d_ws;
  size_t off = 0;
  int*      cnt       = (int*)(ws + off);      off += align256((size_t)N * 4);
  float*    dinv      = (float*)(ws + off);    off += align256((size_t)N * 4);
  int*      base      = (int*)(ws + off);      off += align256((size_t)N * 4);
  int*      binCnt    = (int*)(ws + off);      off += align256(512 * 4);
  int*      binBase   = (int*)(ws + off);      off += align256(512 * 4);
  int*      binCursor = (int*)(ws + off);      off += align256(512 * 4);
  unsigned short* w1t = (unsigned short*)(ws + off); off += align256((size_t)HID_DIM * IN_DIM * 2);
  unsigned* entry1    = (unsigned*)(ws + off); off += align256((size_t)E * 4);
  int*      entry2    = (int*)(ws + off);      off += align256(e2cap * 4);
  unsigned* xw1b      = (unsigned*)(ws + off); off += align256((size_t)(N + 1) * (HID_DIM / 2) * 4);
  unsigned* xw2b      = (unsigned*)(ws + off); off += align256((size_t)(N + 1) * (OUT_DIM / 2) * 4);
  float*    outf      = (float*)d_out;

  hipMemsetAsync(binCnt, 0, 512 * 4, stream);

  k_p1<<<np, 256, 0, stream>>>(eidx, E, binCnt, (long long)N, nbin);
  k_scanbins<<<1, 512, 0, stream>>>(binCnt, binBase, binCursor, nbin, W1, w1t, xw1b, xw2b, N);
  k_p2<<<np, 256, 0, stream>>>(eidx, E, binCursor, entry1, (long long)N, nbin);
  k_p3<<<nbin, 256, 0, stream>>>(entry1, binBase, binCnt, entry2, base, cnt, dinv, N);

  k_gemm1<<<(N + 63) / 64, 256, 0, stream>>>(x, w1t, dinv, xw1b, N);

  k_gather1<<<(N + 15) / 16, 256, 0, stream>>>(entry2, base, cnt, dinv,
                                               (const uint2*)xw1b, b1, W2, xw2b, N);

  k_gather2<<<(N + 31) / 32, 256, 0, stream>>>(entry2, base, cnt, dinv,
                                               (const uint2*)xw2b, b2, outf, N);
}